// Round 11
// baseline (379.785 us; speedup 1.0000x reference)
//
#include <hip/hip_runtime.h>
#include <cstdint>
#include <cstddef>

// GAT layer, N=8192, Fin=128, Fout=64.
// h = elu( softmax_j(mask(leaky_relu(Wh1_i + Wh2_j))) @ Wh )
// R15 = R14 with ONE change: adj prefetch issued in 4-block BURSTS (16
// back-to-back loads, row-major order, sched_barrier-fenced), double-buffered
// across two 4-block register sets. Same bytes, same occupancy. Theory: every
// adj variant has capped at 2.8-3.3 TB/s read service while write fills hit
// 6.6 -- each 128B request opens its own DRAM page (rows 32KB apart), and
// R14's one-block-per-body refill spaced same-row chunks ~400cy apart. The
// burst puts each row's 512B in the controller queue simultaneously -> 4
// page-hits per activation.

#define NN   8192
#define FIN  128
#define FOUT 64
#define SJ   16                // j-split per 32-row group: 256*SJ = 4096 tasks
#define JCHUNK (NN / SJ)       // 512 columns per wave -> 16 blocks of 32

typedef __attribute__((ext_vector_type(8))) short   short8;   // 8 bf16 (4 VGPRs)
typedef __attribute__((ext_vector_type(4))) float   f32x4;

#define LOG2E 1.44269504088896340736f
#define NTL(p) __builtin_nontemporal_load((const f32x4*)(p))

// ---------------------------------------------------------------- Phase A ---
// One wave per 4 rows: Wh[row][f] (f = lane). Emits:
//  - WhP packed B-fragments: WhP[(B0*4+ft)*512 + lane*8 + e] =
//      bf16(Wh[B0*32 + (lane>>4)*8 + e][ (ft*16) + (lane&15) ])
//    i.e. exactly the 16B lane (m,q) consumes as MFMA-B in phaseB.
//  - Wh1/Wh2 = Wh.a1 / Wh.a2, pre-scaled by log2e (exp2 domain; leaky_relu
//    commutes with positive scaling).
__global__ __launch_bounds__(256) void gat_phaseA(
    const float* __restrict__ x, const float* __restrict__ W,
    const float* __restrict__ a, unsigned short* __restrict__ WhP,
    float* __restrict__ Wh1, float* __restrict__ Wh2)
{
  const int wid  = threadIdx.x >> 6;
  const int lane = threadIdx.x & 63;
  const int row0 = (blockIdx.x * 4 + wid) * 4;
  const float a1 = a[lane];
  const float a2 = a[FOUT + lane];
  float acc[4] = {0.f, 0.f, 0.f, 0.f};
#pragma unroll 4
  for (int k = 0; k < FIN; k += 4) {
    float4 wv0 = make_float4(W[(k+0)*FOUT + lane], W[(k+1)*FOUT + lane],
                             W[(k+2)*FOUT + lane], W[(k+3)*FOUT + lane]);
#pragma unroll
    for (int r = 0; r < 4; ++r) {
      float4 xv = *(const float4*)(x + (row0 + r) * FIN + k);
      acc[r] = fmaf(xv.x, wv0.x, acc[r]);
      acc[r] = fmaf(xv.y, wv0.y, acc[r]);
      acc[r] = fmaf(xv.z, wv0.z, acc[r]);
      acc[r] = fmaf(xv.w, wv0.w, acc[r]);
    }
  }
  const int ft = lane >> 4, m = lane & 15;
#pragma unroll
  for (int r = 0; r < 4; ++r) {
    const int row = row0 + r;
    // bf16 round-to-nearest-even
    unsigned int u = __float_as_uint(acc[r]);
    unsigned int rb = (u + 0x7FFFu + ((u >> 16) & 1u)) >> 16;
    // packed-fragment dest: B0=row>>5, q=(row>>3)&3, e=row&7
    const int B0 = row >> 5, qq = (row >> 3) & 3, e = row & 7;
    WhP[(size_t)(B0 * 4 + ft) * 512 + (qq * 16 + m) * 8 + e] = (unsigned short)rb;
    float s1 = acc[r] * a1, s2 = acc[r] * a2;
#pragma unroll
    for (int off = 32; off; off >>= 1) {
      s1 += __shfl_xor(s1, off);
      s2 += __shfl_xor(s2, off);
    }
    if (lane == 0) { Wh1[row] = s1 * LOG2E; Wh2[row] = s2 * LOG2E; }
  }
}

// ---------------------------------------------------------------- Phase B ---
// Wave task = (rowGroup of 32 rows) x (j-chunk of 512). 4 waves/WG share the
// j-chunk; packed-B panel (64 KB) + Wh2 chunk (2 KB) in LDS. Body reads B/w2
// from LDS (lgkmcnt); adj is the only vmcnt user, refilled in 4-block bursts
// (16 loads back-to-back, row-major) every 4 bodies, 2 register sets deep.
#define AF_ONE(AF, AD0, AD1, W20, W21, WH1, RS)                          \
    _Pragma("unroll")                                                    \
    for (int e = 0; e < 4; ++e) {                                        \
      float t0 = (WH1) + (W20)[e];                                       \
      t0 = fmaxf(t0, 0.2f * t0);            /* leaky_relu, scale-inv */  \
      float p0 = exp2f(t0) * (AD0)[e];      /* mask: adj is 0.0/1.0 */   \
      unsigned int pu0 = __float_as_uint(p0) & 0xFFFF0000u;              \
      RS += __uint_as_float(pu0);           /* denom matches bf16 num */ \
      AF[e] = (short)(pu0 >> 16);                                        \
      float t1 = (WH1) + (W21)[e];                                       \
      t1 = fmaxf(t1, 0.2f * t1);                                         \
      float p1 = exp2f(t1) * (AD1)[e];                                   \
      unsigned int pu1 = __float_as_uint(p1) & 0xFFFF0000u;              \
      RS += __uint_as_float(pu1);                                        \
      AF[4 + e] = (short)(pu1 >> 16);                                    \
    }

#define GAT_BODY(AD00, AD01, AD10, AD11, BLK)                            \
  {                                                                      \
    const unsigned short* pb = panel + (BLK) * 2048 + lane * 8;          \
    short8 b0 = *(const short8*)(pb);                                    \
    short8 b1 = *(const short8*)(pb + 512);                              \
    short8 b2 = *(const short8*)(pb + 1024);                             \
    short8 b3 = *(const short8*)(pb + 1536);                             \
    const float* wp = w2lds + (BLK) * 32 + q * 8;                        \
    f32x4 w20 = *(const f32x4*)(wp);                                     \
    f32x4 w21 = *(const f32x4*)(wp + 4);                                 \
    short8 af0, af1;                                                     \
    AF_ONE(af0, AD00, AD01, w20, w21, wh1_0, rsum0);                     \
    AF_ONE(af1, AD10, AD11, w20, w21, wh1_1, rsum1);                     \
    c00 = __builtin_amdgcn_mfma_f32_16x16x32_bf16(af0, b0, c00, 0,0,0);  \
    c01 = __builtin_amdgcn_mfma_f32_16x16x32_bf16(af0, b1, c01, 0,0,0);  \
    c02 = __builtin_amdgcn_mfma_f32_16x16x32_bf16(af0, b2, c02, 0,0,0);  \
    c03 = __builtin_amdgcn_mfma_f32_16x16x32_bf16(af0, b3, c03, 0,0,0);  \
    c10 = __builtin_amdgcn_mfma_f32_16x16x32_bf16(af1, b0, c10, 0,0,0);  \
    c11 = __builtin_amdgcn_mfma_f32_16x16x32_bf16(af1, b1, c11, 0,0,0);  \
    c12 = __builtin_amdgcn_mfma_f32_16x16x32_bf16(af1, b2, c12, 0,0,0);  \
    c13 = __builtin_amdgcn_mfma_f32_16x16x32_bf16(af1, b3, c13, 0,0,0);  \
  }

// burst-refill 4 blocks (J..J+96 floats): row-major order so each adj row's
// 512B sits in the controller queue within a few cycles (page-hit friendly)
#define ADJ_BURST(P0,P1,P2,P3, Q0,Q1,Q2,Q3, R0,R1,R2,R3, S0,S1,S2,S3, J)\
    P0 = NTL(adjrow0 + (J));        P1 = NTL(adjrow0 + (J) + 4);         \
    Q0 = NTL(adjrow0 + (J) + 32);   Q1 = NTL(adjrow0 + (J) + 36);        \
    R0 = NTL(adjrow0 + (J) + 64);   R1 = NTL(adjrow0 + (J) + 68);        \
    S0 = NTL(adjrow0 + (J) + 96);   S1 = NTL(adjrow0 + (J) + 100);       \
    P2 = NTL(adjrow1 + (J));        P3 = NTL(adjrow1 + (J) + 4);         \
    Q2 = NTL(adjrow1 + (J) + 32);   Q3 = NTL(adjrow1 + (J) + 36);        \
    R2 = NTL(adjrow1 + (J) + 64);   R3 = NTL(adjrow1 + (J) + 68);        \
    S2 = NTL(adjrow1 + (J) + 96);   S3 = NTL(adjrow1 + (J) + 100);

__global__ __launch_bounds__(256, 2) void gat_phaseB(
    const float* __restrict__ adj, const unsigned short* __restrict__ WhP,
    const float* __restrict__ Wh1, const float* __restrict__ Wh2,
    float* __restrict__ accbuf, float* __restrict__ denbuf, int nslices)
{
  const int wid  = threadIdx.x >> 6;
  const int lane = threadIdx.x & 63;
  // 4 waves of a WG share the j-chunk, cover 4 row-groups
  const int jc   = blockIdx.x % SJ;
  const int rg   = (blockIdx.x / SJ) * 4 + wid;   // 32-row group
  const int m = lane & 15;
  const int q = lane >> 4;
  const int r0 = rg * 32 + m;
  const int r1 = r0 + 16;
  const float wh1_0 = Wh1[r0];
  const float wh1_1 = Wh1[r1];
  // per-lane bases with the q*8 element offset folded in
  const float* adjrow0 = adj + (size_t)r0 * NN + q * 8;
  const float* adjrow1 = adj + (size_t)r1 * NN + q * 8;

  const int jbeg = jc * JCHUNK;

  // two 4-block register sets (A-D = even group, E-H = odd group)
  f32x4 pA0,pA1,pA2,pA3, pB0,pB1,pB2,pB3, pC0,pC1,pC2,pC3, pD0,pD1,pD2,pD3;
  f32x4 pE0,pE1,pE2,pE3, pF0,pF1,pF2,pF3, pG0,pG1,pG2,pG3, pH0,pH1,pH2,pH3;

  // prologue bursts: blocks 0-3 and 4-7
  ADJ_BURST(pA0,pA1,pA2,pA3, pB0,pB1,pB2,pB3, pC0,pC1,pC2,pC3,
            pD0,pD1,pD2,pD3, jbeg);
  ADJ_BURST(pE0,pE1,pE2,pE3, pF0,pF1,pF2,pF3, pG0,pG1,pG2,pG3,
            pH0,pH1,pH2,pH3, jbeg + 128);

  // ---- LDS: 64 KB packed-B panel + 2 KB Wh2 chunk for this jc
  __shared__ __align__(16) unsigned short panel[16 * 2048];
  __shared__ __align__(16) float w2lds[JCHUNK];
  {
    const f32x4* src = (const f32x4*)(WhP + (size_t)jc * 16 * 2048) + threadIdx.x;
    f32x4* dst = (f32x4*)panel + threadIdx.x;
#pragma unroll
    for (int k = 0; k < 16; ++k)
      dst[k * 256] = src[k * 256];     // 256 thr x 16B = 4 KB per step
    if (threadIdx.x < JCHUNK / 4)
      ((f32x4*)w2lds)[threadIdx.x] =
          ((const f32x4*)(Wh2 + jbeg))[threadIdx.x];
  }
  __syncthreads();

  f32x4 c00 = {0.f,0.f,0.f,0.f}, c01 = c00, c02 = c00, c03 = c00;
  f32x4 c10 = c00, c11 = c00, c12 = c00, c13 = c00;
  float rsum0 = 0.f, rsum1 = 0.f;

  // group 0: bodies 0-3 from set0, then burst-refill set0 with blocks 8-11
  GAT_BODY(pA0, pA1, pA2, pA3, 0);
  GAT_BODY(pB0, pB1, pB2, pB3, 1);
  GAT_BODY(pC0, pC1, pC2, pC3, 2);
  GAT_BODY(pD0, pD1, pD2, pD3, 3);
  __builtin_amdgcn_sched_barrier(0);
  ADJ_BURST(pA0,pA1,pA2,pA3, pB0,pB1,pB2,pB3, pC0,pC1,pC2,pC3,
            pD0,pD1,pD2,pD3, jbeg + 256);
  __builtin_amdgcn_sched_barrier(0);
  // group 1: bodies 4-7 from set1, then burst-refill set1 with blocks 12-15
  GAT_BODY(pE0, pE1, pE2, pE3, 4);
  GAT_BODY(pF0, pF1, pF2, pF3, 5);
  GAT_BODY(pG0, pG1, pG2, pG3, 6);
  GAT_BODY(pH0, pH1, pH2, pH3, 7);
  __builtin_amdgcn_sched_barrier(0);
  ADJ_BURST(pE0,pE1,pE2,pE3, pF0,pF1,pF2,pF3, pG0,pG1,pG2,pG3,
            pH0,pH1,pH2,pH3, jbeg + 384);
  __builtin_amdgcn_sched_barrier(0);
  // group 2: bodies 8-11 from set0 (no further refill needed)
  GAT_BODY(pA0, pA1, pA2, pA3, 8);
  GAT_BODY(pB0, pB1, pB2, pB3, 9);
  GAT_BODY(pC0, pC1, pC2, pC3, 10);
  GAT_BODY(pD0, pD1, pD2, pD3, 11);
  // group 3: bodies 12-15 from set1
  GAT_BODY(pE0, pE1, pE2, pE3, 12);
  GAT_BODY(pF0, pF1, pF2, pF3, 13);
  GAT_BODY(pG0, pG1, pG2, pG3, 14);
  GAT_BODY(pH0, pH1, pH2, pH3, 15);

  // row-sums: combine the 4 k-quads; every lane ends with full sum for its m
  rsum0 += __shfl_xor(rsum0, 16);
  rsum0 += __shfl_xor(rsum0, 32);
  rsum1 += __shfl_xor(rsum1, 16);
  rsum1 += __shfl_xor(rsum1, 32);

  const int slice = (nslices > 1) ? jc : 0;
  float* accout = accbuf + (size_t)slice * (NN * FOUT);
  float* denout = denbuf + slice * NN;
  f32x4 cc0[4] = {c00, c01, c02, c03};
  f32x4 cc1[4] = {c10, c11, c12, c13};
  if (nslices > 1) {            // roomy ws: plain per-slice stores
    if (q == 0) { denout[r0] = rsum0; denout[r1] = rsum1; }
#pragma unroll
    for (int ft = 0; ft < 4; ++ft)
#pragma unroll
      for (int r = 0; r < 4; ++r) {
        accout[(rg * 32 +      q * 4 + r) * FOUT + ft * 16 + m] = cc0[ft][r];
        accout[(rg * 32 + 16 + q * 4 + r) * FOUT + ft * 16 + m] = cc1[ft][r];
      }
  } else {                      // tight ws: atomic accumulate (zeroed first)
    if (q == 0) { atomicAdd(&denout[r0], rsum0); atomicAdd(&denout[r1], rsum1); }
#pragma unroll
    for (int ft = 0; ft < 4; ++ft)
#pragma unroll
      for (int r = 0; r < 4; ++r) {
        atomicAdd(&accout[(rg * 32 +      q * 4 + r) * FOUT + ft * 16 + m], cc0[ft][r]);
        atomicAdd(&accout[(rg * 32 + 16 + q * 4 + r) * FOUT + ft * 16 + m], cc1[ft][r]);
      }
  }
}

// ---------------------------------------------------------------- Phase C ---
// elu(acc/den), vectorized f32x4 per thread.
__global__ __launch_bounds__(256) void gat_phaseC(
    const float* __restrict__ accbuf, const float* __restrict__ denbuf,
    float* __restrict__ out, int nslices)
{
  const int idx4 = blockIdx.x * 256 + threadIdx.x;   // f32x4 index
  const int idx  = idx4 * 4;
  const int row  = idx >> 6;    // FOUT = 64; 4 elems stay within one row
  f32x4 s = {0.f, 0.f, 0.f, 0.f};
  float d = 0.f;
  for (int sl = 0; sl < nslices; ++sl) {
    f32x4 v = *(const f32x4*)(accbuf + (size_t)sl * (NN * FOUT) + idx);
    s += v;
    d += denbuf[sl * NN + row];
  }
  float inv = 1.0f / d;
  f32x4 o;
#pragma unroll
  for (int e = 0; e < 4; ++e) {
    float v = s[e] * inv;
    o[e] = (v > 0.f) ? v : expm1f(v);   // elu, alpha=1
  }
  *(f32x4*)(out + idx) = o;
}

// ------------------------------------------------------------------ launch --
extern "C" void kernel_launch(void* const* d_in, const int* in_sizes, int n_in,
                              void* d_out, int out_size, void* d_ws, size_t ws_size,
                              hipStream_t stream)
{
  const float* x   = (const float*)d_in[0];   // [8192,128]
  const float* adj = (const float*)d_in[1];   // [8192,8192]
  const float* W   = (const float*)d_in[2];   // [128,64]
  const float* a   = (const float*)d_in[3];   // [128,1]
  float* out = (float*)d_out;                 // [8192,64] fp32

  const size_t accEl = (size_t)NN * FOUT;
  const size_t whpBytes = (size_t)(NN / 32) * 4 * 512 * 2;   // 1 MB packed B
  const size_t roomyBytes = (size_t)SJ * accEl * 4 + (size_t)SJ * NN * 4
                          + (size_t)NN * 8 + whpBytes;
  const int nslices = (ws_size >= roomyBytes) ? SJ : 1;

  char* ws = (char*)d_ws;
  float* accbuf = (float*)ws;
  size_t off = (size_t)nslices * accEl * 4;
  float* denbuf = (float*)(ws + off); off += (size_t)nslices * NN * 4;
  float* Wh1 = (float*)(ws + off);    off += (size_t)NN * 4;
  float* Wh2 = (float*)(ws + off);    off += (size_t)NN * 4;
  unsigned short* WhP = (unsigned short*)(ws + off);

  if (nslices == 1)   // atomic path needs zeroed acc+den (contiguous)
    hipMemsetAsync(accbuf, 0, accEl * 4 + (size_t)NN * 4, stream);

  gat_phaseA<<<NN / 16, 256, 0, stream>>>(x, W, a, WhP, Wh1, Wh2);
  gat_phaseB<<<((NN / 32) * SJ) / 4, 256, 0, stream>>>(adj, WhP, Wh1, Wh2,
                                                       accbuf, denbuf, nslices);
  gat_phaseC<<<(NN * FOUT) / 4 / 256, 256, 0, stream>>>(accbuf, denbuf, out, nslices);
}